// Round 6
// baseline (733.880 us; speedup 1.0000x reference)
//
#include <hip/hip_runtime.h>

// GRU encoder: B=64, T=512, F=64, H=256, D=64.
//   k1: xproj = x @ kernel + bias -> f16 in d_ws, dot2-based GEMM (unchanged).
//   k2: per-batch scan, 64 blocks x 1024 threads.
//       Round-6: matvec moved from VALU (96 dot2 @ ~4cyc = the measured
//       bottleneck, MfmaUtil=0) to the idle matrix pipe: 24x
//       mfma_f32_16x16x32_f16 per wave per step, M=1 (A rows 1..15 = zeros
//       from a zeroed LDS region). W_rec stays in 96 regs as B-fragments
//       (AGPR-friendly: MFMA reads B from AGPR natively). A and B packed
//       with the SAME k->(reg,lane-group) bijection, so the exact hardware
//       k-ordering of the x32 fragment cancels out. Gates unchanged on
//       lanes 0..15 of each wave (16 waves x 16 cols = 256). One barrier
//       per step via double-buffered h.

typedef _Float16 half2_t __attribute__((ext_vector_type(2)));
typedef _Float16 f16x4_t __attribute__((ext_vector_type(4)));
typedef _Float16 f16x8_t __attribute__((ext_vector_type(8)));
typedef float f32x4_t __attribute__((ext_vector_type(4)));

#define LOG2E 1.4426950408889634f

__device__ __forceinline__ float fast_sigmoid(float x) {
  float e = __builtin_amdgcn_exp2f(-x * LOG2E);
  return __builtin_amdgcn_rcpf(1.0f + e);
}
__device__ __forceinline__ float fast_tanh(float x) {
  float e = __builtin_amdgcn_exp2f(x * (2.0f * LOG2E));
  return 1.0f - 2.0f * __builtin_amdgcn_rcpf(1.0f + e);
}

// ---------------------------------------------------------------------------
// Kernel 1: xproj GEMM.  C(32768x768) = A(32768x64) @ B(64x768) + bias.
// (unchanged)
// ---------------------------------------------------------------------------
__global__ __launch_bounds__(256, 4) void xproj_gemm(
    const float* __restrict__ x, const float* __restrict__ kmat,
    const float* __restrict__ bias, _Float16* __restrict__ xp) {
  __shared__ half2_t As2[32][132];  // [kpair][row]
  __shared__ half2_t Bs2[32][132];  // [kpair][col]
  const int tid = threadIdx.x;
  const int rb = blockIdx.x * 128;
  const int cb = blockIdx.y * 128;

  {
    const int k4 = (tid & 15) * 4;
    const int r0 = tid >> 4;
#pragma unroll
    for (int p = 0; p < 8; ++p) {
      int r = r0 + p * 16;
      float4 v = *(const float4*)(x + (size_t)(rb + r) * 64 + k4);
      half2_t lo, hi;
      lo[0] = (_Float16)v.x; lo[1] = (_Float16)v.y;
      hi[0] = (_Float16)v.z; hi[1] = (_Float16)v.w;
      As2[k4 / 2][r] = lo;
      As2[k4 / 2 + 1][r] = hi;
    }
  }
  {
    const int c4 = (tid & 31) * 4;
    const int kp0 = tid >> 5;
#pragma unroll
    for (int p = 0; p < 4; ++p) {
      int kp = kp0 + p * 8;
      float4 va = *(const float4*)(kmat + (size_t)(2 * kp) * 768 + cb + c4);
      float4 vb = *(const float4*)(kmat + (size_t)(2 * kp + 1) * 768 + cb + c4);
      half2_t o0, o1, o2, o3;
      o0[0] = (_Float16)va.x; o0[1] = (_Float16)vb.x;
      o1[0] = (_Float16)va.y; o1[1] = (_Float16)vb.y;
      o2[0] = (_Float16)va.z; o2[1] = (_Float16)vb.z;
      o3[0] = (_Float16)va.w; o3[1] = (_Float16)vb.w;
      Bs2[kp][c4 + 0] = o0;
      Bs2[kp][c4 + 1] = o1;
      Bs2[kp][c4 + 2] = o2;
      Bs2[kp][c4 + 3] = o3;
    }
  }
  __syncthreads();

  const int tx = tid & 15, ty = tid >> 4;
  const int r0 = ty * 8;
  const int c0 = tx * 4;
  float acc[8][8];
  {
    float4 b0 = *(const float4*)(bias + cb + c0);
    float4 b1 = *(const float4*)(bias + cb + 64 + c0);
    float bz[8] = {b0.x, b0.y, b0.z, b0.w, b1.x, b1.y, b1.z, b1.w};
#pragma unroll
    for (int i = 0; i < 8; ++i)
#pragma unroll
      for (int j = 0; j < 8; ++j) acc[i][j] = bz[j];
  }

#pragma unroll 2
  for (int kp = 0; kp < 32; ++kp) {
    half2_t a2[8], b2[8];
    *(int4*)(&a2[0]) = *(const int4*)(&As2[kp][r0]);
    *(int4*)(&a2[4]) = *(const int4*)(&As2[kp][r0 + 4]);
    *(int2*)(&b2[0]) = *(const int2*)(&Bs2[kp][c0]);
    *(int2*)(&b2[2]) = *(const int2*)(&Bs2[kp][c0 + 2]);
    *(int2*)(&b2[4]) = *(const int2*)(&Bs2[kp][64 + c0]);
    *(int2*)(&b2[6]) = *(const int2*)(&Bs2[kp][64 + c0 + 2]);
#pragma unroll
    for (int i = 0; i < 8; ++i)
#pragma unroll
      for (int j = 0; j < 8; ++j)
        acc[i][j] = __builtin_amdgcn_fdot2(a2[i], b2[j], acc[i][j], false);
  }

#pragma unroll
  for (int i = 0; i < 8; ++i) {
    f16x4_t o0, o1;
#pragma unroll
    for (int j = 0; j < 4; ++j) {
      o0[j] = (_Float16)acc[i][j];
      o1[j] = (_Float16)acc[i][4 + j];
    }
    _Float16* dst = xp + (size_t)(rb + r0 + i) * 768 + cb;
    *(f16x4_t*)(dst + c0) = o0;
    *(f16x4_t*)(dst + 64 + c0) = o1;
  }
}

// ---------------------------------------------------------------------------
// Kernel 2: GRU scan, MFMA edition. One block per batch. 1024 thr = 16 waves.
// Wave w owns output cols w*16..w*16+15 for all 3 gates.
// B-frag (W_rec): wf[g][s][j] = W[k = s*32 + (lane>>4)*8 + j][g*256 + col],
//   col = w*16 + (lane&15). 96 regs/thread (-> AGPRs).
// A-frag (h):     a[j]        = h[k = s*32 + (lane>>4)*8 + j] for lanes with
//   (lane&15)==0, zeros otherwise (rows 1..15 of the M=16 tile unused).
//   Same k-bijection as B, so hardware fragment ordering cancels.
// D: row = (lane>>4)*4 + reg, col = lane&15  [m89-verified] -> row 0 lives
//   in reg 0 of lanes 0..15: gates run on lanes 0..15 of every wave.
// ---------------------------------------------------------------------------
__global__ __launch_bounds__(1024, 4) void gru_scan(
    const _Float16* __restrict__ xp, const float* __restrict__ wr,
    const float* __restrict__ dw, const float* __restrict__ db,
    float* __restrict__ out, float* __restrict__ state) {
  __shared__ alignas(16) _Float16 zz[256];   // stays zero: A rows 1..15
  __shared__ alignas(16) _Float16 hh0[256];  // h double buffer (f16)
  __shared__ alignas(16) _Float16 hh1[256];
  __shared__ float hbuf[256];

  const int tid = threadIdx.x;
  const int b = blockIdx.x;
  const int lane = tid & 63;
  const int w = tid >> 6;
  const int q = lane >> 4;               // k-subgroup 0..3
  const int col = w * 16 + (lane & 15);  // output column (per gate)
  const bool gl = (lane < 16);           // gate lanes (D row 0)

  // --- W_rec as B-fragments: wf[g][s], elem j -> k = s*32 + q*8 + j.
  f16x8_t wf[3][8];
#pragma unroll
  for (int g = 0; g < 3; ++g)
#pragma unroll
    for (int s = 0; s < 8; ++s) {
      const float* wp = wr + (size_t)(s * 32 + q * 8) * 768 + g * 256 + col;
      f16x8_t v;
#pragma unroll
      for (int j = 0; j < 8; ++j) v[j] = (_Float16)wp[(size_t)j * 768];
      wf[g][s] = v;
    }

  if (tid < 256) {
    zz[tid] = (_Float16)0.0f;
    hh0[tid] = (_Float16)0.0f;
  }
  __syncthreads();

  // Per-lane A base: real h for (lane&15)==0, zero region otherwise.
  // +q*8 folds the lane-group k-offset into the base.
  const bool arow0 = ((lane & 15) == 0);
  const _Float16* ab0 = (arow0 ? hh0 : zz) + q * 8;
  const _Float16* ab1 = (arow0 ? hh1 : zz) + q * 8;

  const _Float16* xpb = xp + (size_t)b * 512 * 768;
  float* outb = out + (size_t)b * 512 * 256;
  float hprev = 0.0f;

#pragma unroll 2
  for (int t = 0; t < 512; ++t) {
    const _Float16* ab = (t & 1) ? ab1 : ab0;  // read buffer
    _Float16* hw = (t & 1) ? hh0 : hh1;        // write buffer

    // Gate lanes: deferred h(t-1) store + x prefetch (consumed after MFMA).
    _Float16 xz = (_Float16)0.0f, xr = (_Float16)0.0f, xh = (_Float16)0.0f;
    if (gl) {
      if (t) outb[(size_t)(t - 1) * 256 + col] = hprev;
      const _Float16* xq = xpb + (size_t)t * 768 + col;
      xz = xq[0];
      xr = xq[256];
      xh = xq[512];
    }

    f32x4_t az = {0.f, 0.f, 0.f, 0.f};
    f32x4_t ar = {0.f, 0.f, 0.f, 0.f};
    f32x4_t ah = {0.f, 0.f, 0.f, 0.f};
#pragma unroll
    for (int s = 0; s < 8; ++s) {
      f16x8_t a = *(const f16x8_t*)(ab + s * 32);  // ds_read_b128, broadcast
      az = __builtin_amdgcn_mfma_f32_16x16x32_f16(a, wf[0][s], az, 0, 0, 0);
      ar = __builtin_amdgcn_mfma_f32_16x16x32_f16(a, wf[1][s], ar, 0, 0, 0);
      ah = __builtin_amdgcn_mfma_f32_16x16x32_f16(a, wf[2][s], ah, 0, 0, 0);
    }

    // Gates: D row 0 = reg 0 of lanes 0..15.
    if (gl) {
      float z = fast_sigmoid((float)xz + az[0]);
      float r = fast_sigmoid((float)xr + ar[0]);
      float hcand = fast_tanh((float)xh + r * ah[0]);
      float hnew = z * hprev + (1.0f - z) * hcand;
      hprev = hnew;
      hw[col] = (_Float16)hnew;
    }
    __syncthreads();  // single barrier per step (double-buffered h)
  }

  if (gl) {
    outb[(size_t)511 * 256 + col] = hprev;
    hbuf[col] = hprev;
  }
  __syncthreads();

  // --- dense head: state[b,:] = tanh(h_last @ dense_w + dense_b)
  if (tid < 64) {
    float acc = db[tid];
#pragma unroll 8
    for (int k = 0; k < 256; ++k) acc = fmaf(hbuf[k], dw[k * 64 + tid], acc);
    state[(size_t)b * 64 + tid] = fast_tanh(acc);
  }
}

// ---------------------------------------------------------------------------
extern "C" void kernel_launch(void* const* d_in, const int* in_sizes, int n_in,
                              void* d_out, int out_size, void* d_ws,
                              size_t ws_size, hipStream_t stream) {
  const float* x = (const float*)d_in[0];     // (64,512,64)
  const float* kmat = (const float*)d_in[1];  // (64,768)
  const float* wr = (const float*)d_in[2];    // (256,768)
  const float* bias = (const float*)d_in[3];  // (768,)
  const float* dw = (const float*)d_in[4];    // (256,64)
  const float* db = (const float*)d_in[5];    // (64,)

  float* out = (float*)d_out;                   // (64,512,256)
  float* state = out + (size_t)64 * 512 * 256;  // (64,64)
  _Float16* xp = (_Float16*)d_ws;               // 64*512*768 f16 = 48 MiB

  dim3 gg(32768 / 128, 768 / 128);
  xproj_gemm<<<gg, 256, 0, stream>>>(x, kmat, bias, xp);
  gru_scan<<<64, 1024, 0, stream>>>(xp, wr, dw, db, out, state);
}